// Round 1
// baseline (66.170 us; speedup 1.0000x reference)
//
#include <hip/hip_runtime.h>
#include <hip/hip_bf16.h>

// Grouped linear: concat(x0..x3) rows [M=294912, K=128] @ W^T[128,128] + bias -> fp32 out.
// bf16 MFMA (16x16x32), W staged once per block in swizzled LDS, x direct global->reg.

typedef __attribute__((ext_vector_type(8))) short bf8_t;   // 8 x bf16 (4 VGPRs)
typedef __attribute__((ext_vector_type(4))) float f4_t;

__device__ __forceinline__ unsigned short f2bf(float f) {
    // RNE fp32 -> bf16 (inputs are finite normals; no NaN handling needed)
    unsigned u = __builtin_bit_cast(unsigned, f);
    u += 0x7fffu + ((u >> 16) & 1u);
    return (unsigned short)(u >> 16);
}

#define SEG0 131072L   // rows in x0 (32*64*64)
#define SEG1 196608L   // + x1 (32*32*64)
#define SEG2 262144L   // + x2 (32*64*32)
// total 294912 rows; all boundaries divisible by 128 -> a 128-row block never straddles

__global__ __launch_bounds__(256)
void lin_kernel(const float* __restrict__ x0, const float* __restrict__ x1,
                const float* __restrict__ x2, const float* __restrict__ x3,
                const float* __restrict__ W, const float* __restrict__ bias,
                float* __restrict__ out)
{
    __shared__ unsigned short Wl[128 * 128]; // bf16 W, row-major 256B rows, 16B-chunk XOR swizzle
    __shared__ float bl[128];

    const int tid = threadIdx.x;

    // ---- stage W: fp32 -> bf16, swizzled (chunk ^= row&7 breaks the 16-way bank conflict) ----
#pragma unroll
    for (int i = 0; i < 16; ++i) {
        int f  = i * 256 + tid;       // float4 index in W, 0..4095
        int n  = f >> 5;              // W row (output feature), 0..127
        int k4 = f & 31;              // float4 index within row
        f4_t v = reinterpret_cast<const f4_t*>(W)[f];
        unsigned long long p =
              (unsigned long long)f2bf(v.x)
            | ((unsigned long long)f2bf(v.y) << 16)
            | ((unsigned long long)f2bf(v.z) << 32)
            | ((unsigned long long)f2bf(v.w) << 48);
        int sc = (k4 >> 1) ^ (n & 7); // swizzled 16B-chunk index
        *reinterpret_cast<unsigned long long*>(&Wl[n * 128 + sc * 8 + (k4 & 1) * 4]) = p;
    }
    if (tid < 128) bl[tid] = bias[tid];
    __syncthreads();

    const int wave = tid >> 6;
    const int lane = tid & 63;
    const int lm   = lane & 15;   // x-row-within-tile (B op cols / D cols)
    const int lk   = lane >> 4;   // 0..3 (k-group / D row group)
    const int nsw  = lm & 7;      // swizzle key for W reads (nrow&7 == lm&7)

    const long blk0 = (long)blockIdx.x * 128;
    const float* xp; long loc;
    if      (blk0 < SEG0) { xp = x0; loc = blk0; }
    else if (blk0 < SEG1) { xp = x1; loc = blk0 - SEG0; }
    else if (blk0 < SEG2) { xp = x2; loc = blk0 - SEG1; }
    else                  { xp = x3; loc = blk0 - SEG2; }

    for (int it = 0; it < 2; ++it) {
        const long r  = (long)it * 64 + wave * 16 + lm;     // row within this block's chunk
        const float* xr = xp + (loc + r) * 128;

        // load 32 fp32 of this row (8 consecutive per k-step), 2x dwordx4 per k-step
        f4_t raw[8];
#pragma unroll
        for (int ks = 0; ks < 4; ++ks) {
            const float* p = xr + ks * 32 + lk * 8;
            raw[2 * ks]     = *reinterpret_cast<const f4_t*>(p);
            raw[2 * ks + 1] = *reinterpret_cast<const f4_t*>(p + 4);
        }
        // convert to bf16 B-fragments (lane holds B[k=lk*8+j][n=lm] = x[row=lm][k])
        bf8_t xf[4];
#pragma unroll
        for (int ks = 0; ks < 4; ++ks) {
            bf8_t t;
            t[0] = (short)f2bf(raw[2 * ks].x);
            t[1] = (short)f2bf(raw[2 * ks].y);
            t[2] = (short)f2bf(raw[2 * ks].z);
            t[3] = (short)f2bf(raw[2 * ks].w);
            t[4] = (short)f2bf(raw[2 * ks + 1].x);
            t[5] = (short)f2bf(raw[2 * ks + 1].y);
            t[6] = (short)f2bf(raw[2 * ks + 1].z);
            t[7] = (short)f2bf(raw[2 * ks + 1].w);
            xf[ks] = t;
        }

        // acc[nt] holds out[row=lm][col = nt*16 + lk*4 + j]; init from bias (broadcast read)
        f4_t acc[8];
#pragma unroll
        for (int nt = 0; nt < 8; ++nt)
            acc[nt] = *reinterpret_cast<const f4_t*>(&bl[nt * 16 + lk * 4]);

        // swapped-operand MFMA: A = W tile (16 out-cols x 32 k), B = x^T
#pragma unroll
        for (int nt = 0; nt < 8; ++nt) {
            const int nrow = nt * 16 + lm;
#pragma unroll
            for (int ks = 0; ks < 4; ++ks) {
                const int c = (ks * 4 + lk) ^ nsw;  // swizzled 16B chunk
                bf8_t wf = *reinterpret_cast<const bf8_t*>(&Wl[nrow * 128 + c * 8]);
                acc[nt] = __builtin_amdgcn_mfma_f32_16x16x32_bf16(wf, xf[ks], acc[nt], 0, 0, 0);
            }
        }

        // coalesced f32x4 stores: lane writes 4 consecutive cols of its row
        float* orow = out + (blk0 + r) * 128;
#pragma unroll
        for (int nt = 0; nt < 8; ++nt)
            *reinterpret_cast<f4_t*>(orow + nt * 16 + lk * 4) = acc[nt];
    }
}

extern "C" void kernel_launch(void* const* d_in, const int* in_sizes, int n_in,
                              void* d_out, int out_size, void* d_ws, size_t ws_size,
                              hipStream_t stream) {
    const float* x0 = (const float*)d_in[0];
    const float* x1 = (const float*)d_in[1];
    const float* x2 = (const float*)d_in[2];
    const float* x3 = (const float*)d_in[3];
    const float* W  = (const float*)d_in[4];
    const float* b  = (const float*)d_in[5];
    float* out = (float*)d_out;

    // 294912 rows / 128 rows per block = 2304 blocks
    hipLaunchKernelGGL(lin_kernel, dim3(2304), dim3(256), 0, stream,
                       x0, x1, x2, x3, W, b, out);
}